// Round 1
// baseline (1752.005 us; speedup 1.0000x reference)
//
#include <hip/hip_runtime.h>
#include <cstdint>
#include <cstddef>

// ---------------------------------------------------------------------------
// Problem constants (B=4096, DIN=DOUT=1024, E=8, K=4)
// ---------------------------------------------------------------------------
#define NB 4096
#define ND 1024

typedef __attribute__((ext_vector_type(8))) short short8v;
typedef __attribute__((ext_vector_type(4))) short short4v;
typedef __attribute__((ext_vector_type(4))) float float4v;

__device__ __forceinline__ unsigned short f2bf(float x){
  union{float f; unsigned u;} v; v.f = x;
  unsigned r = v.u + 0x7FFFu + ((v.u >> 16) & 1u);  // RNE
  return (unsigned short)(r >> 16);
}
__device__ __forceinline__ float bf2f(unsigned short h){
  union{unsigned u; float f;} v; v.u = ((unsigned)h) << 16; return v.f;
}

typedef const __attribute__((address_space(1))) unsigned int* gas_ptr;
typedef __attribute__((address_space(3))) unsigned int* las_ptr;

__device__ __forceinline__ void gload_lds16(const void* g, void* l){
  __builtin_amdgcn_global_load_lds((gas_ptr)g, (las_ptr)l, 16, 0, 0);
}

// ---------------------------------------------------------------------------
// Generic 128x128x(BK=32) bf16 MFMA GEMM, both operands [outer][K] layout.
// KIND 0: fused layer-1 (N=9216, epilogue per 1024-col region)
// KIND 1: fused layer-2 (N=7168, A col-offset per region)
// KIND 2: gate GEMM1 (N=512, K=3072 bf16x3 split, tanh epilogue -> T fp32)
// ---------------------------------------------------------------------------
struct GemmArgs {
  const unsigned short* A;     // bf16 [M][lda]
  const unsigned short* A2;    // xlo (gate only)
  const unsigned short* Bt;    // bf16 [N][K]
  int lda;
  int K;
  const float* bias;           // [N]
  unsigned short* H;           // KIND0 dest (cols 0..7167)
  unsigned short* eoc;         // KIND0 conv dest [2][4096][1024]
  unsigned short* eolin;       // KIND1 dest [6][4096][1024]
  float* outsh;                // KIND1 shared dest (d_out)
  float* T;                    // KIND2 dest [4096][512]
  const float* w1last;         // gate: g_W1 row 1024
  const int* mod;              // modality_id
};

template<int KIND>
__global__ __launch_bounds__(256, 2) void k_gemm(GemmArgs g){
  __shared__ unsigned short sA[128*32];
  __shared__ unsigned short sB[128*32];
  const int tid  = threadIdx.x;
  const int lane = tid & 63;
  const int wid  = tid >> 6;
  const int m0 = blockIdx.x * 128;
  const int n0 = blockIdx.y * 128;
  const int srow   = tid >> 2;        // 0..63
  const int schunk = (tid & 3) * 8;   // k element offset
  const int K   = g.K;
  const int lda = g.lda;

  const unsigned short* Abase0 = g.A + (KIND == 1 ? (size_t)(blockIdx.y >> 3) * 1024 : 0);

  unsigned short* lA0 = &sA[wid * 512];
  unsigned short* lA1 = &sA[2048 + wid * 512];
  unsigned short* lB0 = &sB[wid * 512];
  unsigned short* lB1 = &sB[2048 + wid * 512];

  const int wr = wid >> 1, wc = wid & 1;
  const int fr = lane & 15;
  const int kc = (lane >> 4) * 8;

  float4v acc[4][4];
  #pragma unroll
  for (int i = 0; i < 4; i++)
    #pragma unroll
    for (int j = 0; j < 4; j++) acc[i][j] = (float4v){0.f, 0.f, 0.f, 0.f};

  for (int k0 = 0; k0 < K; k0 += 32){
    const unsigned short* Ab; int acol;
    if (KIND == 2){ int seg = k0 >> 10; Ab = (seg == 1) ? g.A2 : g.A; acol = k0 & 1023; }
    else          { Ab = Abase0; acol = k0; }
    gload_lds16(Ab + (size_t)(m0      + srow) * lda + acol + schunk, lA0);
    gload_lds16(Ab + (size_t)(m0 + 64 + srow) * lda + acol + schunk, lA1);
    gload_lds16(g.Bt + (size_t)(n0      + srow) * K + k0 + schunk, lB0);
    gload_lds16(g.Bt + (size_t)(n0 + 64 + srow) * K + k0 + schunk, lB1);
    __syncthreads();
    short8v a[4], b[4];
    #pragma unroll
    for (int mi = 0; mi < 4; mi++) a[mi] = *(const short8v*)&sA[(wr*64 + mi*16 + fr)*32 + kc];
    #pragma unroll
    for (int ni = 0; ni < 4; ni++) b[ni] = *(const short8v*)&sB[(wc*64 + ni*16 + fr)*32 + kc];
    #pragma unroll
    for (int mi = 0; mi < 4; mi++)
      #pragma unroll
      for (int ni = 0; ni < 4; ni++)
        acc[mi][ni] = __builtin_amdgcn_mfma_f32_16x16x32_bf16(a[mi], b[ni], acc[mi][ni], 0, 0, 0);
    __syncthreads();
  }

  const int mr0 = m0 + wr * 64;
  const int nc0 = n0 + wc * 64;
  #pragma unroll
  for (int ni = 0; ni < 4; ni++){
    const int ncol = nc0 + ni * 16 + fr;
    const float bval = g.bias[ncol];
    #pragma unroll
    for (int mi = 0; mi < 4; mi++){
      const int mrow = mr0 + mi * 16 + (lane >> 4) * 4;
      float4v v = acc[mi][ni];
      #pragma unroll
      for (int r = 0; r < 4; r++){
        float val = v[r] + bval;
        const int m = mrow + r;
        if (KIND == 0){
          const int region = ncol >> 10;
          if (region < 7){
            float o;
            if (region < 2 || region == 6)      o = fmaxf(val, 0.f);           // relu (mlp, shared)
            else if (region < 4)                o = tanhf(val);                // bn experts
            else                                o = val * (1.f/(1.f+expf(-val))); // silu (ln experts)
            g.H[(size_t)m * 7168 + ncol] = f2bf(o);
          } else {
            float o = 0.5f * val * (1.f + erff(val * 0.70710678118654752f));   // exact gelu
            const int e = region - 7, cc = ncol & 1023;
            g.eoc[((size_t)e * NB + m) * 1024 + cc] = f2bf(o);
          }
        } else if (KIND == 1){
          const int region = ncol >> 10, cc = ncol & 1023;
          if (region < 6) g.eolin[((size_t)region * NB + m) * 1024 + cc] = f2bf(val);
          else            g.outsh[(size_t)m * 1024 + cc] = val;                // shared expert
        } else {
          float t = tanhf(val + (float)g.mod[m] * g.w1last[ncol]);
          g.T[(size_t)m * 512 + ncol] = t;
        }
      }
    }
  }
}

// ---------------------------------------------------------------------------
// Prep kernels
// ---------------------------------------------------------------------------
__global__ void k_cast_x(const float* __restrict__ x, unsigned short* __restrict__ xb,
                         unsigned short* __restrict__ xlo){
  int i = blockIdx.x * 256 + threadIdx.x;      // 1M threads, 4 elems each
  float4v v = ((const float4v*)x)[i];
  short4v hi, lo;
  #pragma unroll
  for (int j = 0; j < 4; j++){
    unsigned short h = f2bf(v[j]);
    hi[j] = (short)h;
    lo[j] = (short)f2bf(v[j] - bf2f(h));
  }
  ((short4v*)xb)[i]  = hi;
  ((short4v*)xlo)[i] = lo;
}

struct TpArgs { const float* src[14]; unsigned short* dst[14]; };

__global__ void k_transpose(TpArgs a){
  __shared__ float tile[32][33];
  const float* src = a.src[blockIdx.z];
  unsigned short* dst = a.dst[blockIdx.z];
  const int bx = blockIdx.x, by = blockIdx.y;   // bx: n-tile, by: k-tile
  const int tx = threadIdx.x, ty = threadIdx.y;
  #pragma unroll
  for (int i = 0; i < 32; i += 8)
    tile[ty + i][tx] = src[(size_t)(by*32 + ty + i) * 1024 + bx*32 + tx];
  __syncthreads();
  #pragma unroll
  for (int i = 0; i < 32; i += 8)
    dst[(size_t)(bx*32 + ty + i) * 1024 + by*32 + tx] = f2bf(tile[tx][ty + i]);
}

__global__ void k_gateW(const float* __restrict__ gW1, unsigned short* __restrict__ Wg3t){
  __shared__ float tile[32][33];
  const int bx = blockIdx.x, by = blockIdx.y;   // bx: k-tile(32), by: n-tile(16)
  const int tx = threadIdx.x, ty = threadIdx.y;
  #pragma unroll
  for (int i = 0; i < 32; i += 8)
    tile[ty + i][tx] = gW1[(size_t)(bx*32 + ty + i) * 512 + by*32 + tx];
  __syncthreads();
  #pragma unroll
  for (int i = 0; i < 32; i += 8){
    int n = by*32 + ty + i, k = bx*32 + tx;
    float v = tile[tx][ty + i];
    unsigned short hi = f2bf(v);
    unsigned short lo = f2bf(v - bf2f(hi));
    Wg3t[(size_t)n*3072 + k]        = hi;
    Wg3t[(size_t)n*3072 + 1024 + k] = hi;
    Wg3t[(size_t)n*3072 + 2048 + k] = lo;
  }
}

// conv1d+flatten+linear == linear with transformed weight; builds W1t rows 7168..9215 + b'
__global__ __launch_bounds__(128) void k_convW(const float* __restrict__ convk, const float* __restrict__ convb,
    const float* __restrict__ convW, const float* __restrict__ convbL,
    unsigned short* __restrict__ W1t, float* __restrict__ b1cat){
  const int e = blockIdx.y;
  const int o = blockIdx.x * 128 + threadIdx.x;
  const float* W = convW + (size_t)e * 4096 * 1024;
  float kk[4][3];
  #pragma unroll
  for (int c = 0; c < 4; c++)
    #pragma unroll
    for (int j = 0; j < 3; j++) kk[c][j] = convk[e*12 + c*3 + j];
  unsigned short* drow = W1t + (size_t)(7168 + e*1024 + o) * 1024;
  float wprev[4], wcur[4], wnext[4], sc[4];
  #pragma unroll
  for (int c = 0; c < 4; c++){
    wprev[c] = 0.f;
    wcur[c]  = W[(size_t)(c*1024) * 1024 + o];
    sc[c]    = wcur[c];
  }
  for (int ip = 0; ip < 1024; ip++){
    #pragma unroll
    for (int c = 0; c < 4; c++){
      wnext[c] = (ip < 1023) ? W[(size_t)(c*1024 + ip + 1) * 1024 + o] : 0.f;
      sc[c]   += (ip < 1023) ? wnext[c] : 0.f;
    }
    float acc = 0.f;
    #pragma unroll
    for (int c = 0; c < 4; c++)
      acc += kk[c][0]*wnext[c] + kk[c][1]*wcur[c] + kk[c][2]*wprev[c];
    drow[ip] = f2bf(acc);
    #pragma unroll
    for (int c = 0; c < 4; c++){ wprev[c] = wcur[c]; wcur[c] = wnext[c]; }
  }
  float bacc = convbL[e*1024 + o];
  #pragma unroll
  for (int c = 0; c < 4; c++) bacc += convb[e*4 + c] * sc[c];
  b1cat[7168 + e*1024 + o] = bacc;
}

__global__ void k_biases(const float* mlp_b1, const float* bn_b1, const float* ln_b1, const float* sh_b1,
                         const float* mlp_b2, const float* bn_b2, const float* ln_b2, const float* sh_b2,
                         float* b1cat, float* b2cat){
  int i = blockIdx.x * 256 + threadIdx.x;   // 14336
  if (i < 7168){
    int r = i >> 10;
    float v;
    if (r < 2) v = mlp_b1[i];
    else if (r < 4) v = bn_b1[i - 2048];
    else if (r < 6) v = ln_b1[i - 4096];
    else v = sh_b1[i - 6144];
    b1cat[i] = v;
  } else {
    int j = i - 7168;
    int r = j >> 10;
    float v;
    if (r < 2) v = mlp_b2[j];
    else if (r < 4) v = bn_b2[j - 2048];
    else if (r < 6) v = ln_b2[j - 4096];
    else v = sh_b2[j - 6144];
    b2cat[j] = v;
  }
}

// ---------------------------------------------------------------------------
// Gate finalize: fp32 logits GEMM2 (512x8), clip, top-4, softmax weights, usage
// ---------------------------------------------------------------------------
__global__ __launch_bounds__(256) void k_gate_fin(const float* __restrict__ T, const float* __restrict__ gW2,
                                                  const float* __restrict__ gb2,
                                                  float* __restrict__ wgt, double* __restrict__ usage){
  const int tok  = blockIdx.x * 4 + (threadIdx.x >> 6);
  const int lane = threadIdx.x & 63;
  const int e = lane >> 3, sub = lane & 7;
  const float* tr = T + (size_t)tok * 512;
  float p = 0.f;
  for (int k = sub; k < 512; k += 8) p += tr[k] * gW2[k*8 + e];
  p += __shfl_xor(p, 1); p += __shfl_xor(p, 2); p += __shfl_xor(p, 4);
  float le[8];
  #pragma unroll
  for (int q = 0; q < 8; q++) le[q] = __shfl(p, q * 8);
  #pragma unroll
  for (int q = 0; q < 8; q++){
    float l = (le[q] + gb2[q]) / 0.7f;
    le[q] = fminf(fmaxf(l, -10.f), 10.f);
  }
  unsigned sel = 0; int idx4[4]; float bv4[4];
  #pragma unroll
  for (int t4 = 0; t4 < 4; t4++){
    float best = -1e30f; int bi = 0;
    for (int q = 0; q < 8; q++)
      if (!((sel >> q) & 1u) && le[q] > best){ best = le[q]; bi = q; }
    sel |= 1u << bi; idx4[t4] = bi; bv4[t4] = best;
  }
  const float mx = bv4[0];                 // global max
  float s4 = 0.f, w4[4];
  #pragma unroll
  for (int t4 = 0; t4 < 4; t4++){ w4[t4] = expf(bv4[t4] - mx); s4 += w4[t4]; }
  float su = 0.f, us[8];
  #pragma unroll
  for (int q = 0; q < 8; q++){ us[q] = expf(le[q] - mx); su += us[q]; }
  if (lane == 0){
    float wr[8] = {0,0,0,0,0,0,0,0};
    #pragma unroll
    for (int t4 = 0; t4 < 4; t4++) wr[idx4[t4]] = w4[t4] / s4;
    #pragma unroll
    for (int q = 0; q < 8; q++) wgt[(size_t)tok*8 + q] = wr[q];
    #pragma unroll
    for (int q = 0; q < 8; q++) atomicAdd(&usage[q], (double)(us[q] / su));
  }
}

__global__ void k_aux(const double* __restrict__ usage, float* __restrict__ auxp){
  if (threadIdx.x == 0 && blockIdx.x == 0){
    float a = 0.f;
    for (int q = 0; q < 8; q++){
      float u = (float)(usage[q] * (1.0 / 4096.0));
      a += 0.125f * (-2.0794415f - logf(u + 1e-10f));
    }
    auxp[0] = a * 0.125f;
  }
}

// ---------------------------------------------------------------------------
// BatchNorm (batch stats) over H cols 2048..4095, in place
// ---------------------------------------------------------------------------
__global__ __launch_bounds__(256) void k_bn(unsigned short* __restrict__ H,
                                            const float* __restrict__ bn_g, const float* __restrict__ bn_be){
  const int cl = threadIdx.x & 63;
  const int rg = threadIdx.x >> 6;
  const int c  = blockIdx.x * 64 + cl;      // 0..2047
  unsigned short* col = H + 2048 + c;
  float s = 0.f, s2 = 0.f;
  for (int r = rg; r < NB; r += 4){ float v = bf2f(col[(size_t)r * 7168]); s += v; s2 += v*v; }
  __shared__ float sm[256], sq[256], smul[64], sadd[64];
  sm[threadIdx.x] = s; sq[threadIdx.x] = s2;
  __syncthreads();
  if (rg == 0){
    float ts = sm[cl] + sm[64+cl] + sm[128+cl] + sm[192+cl];
    float tq = sq[cl] + sq[64+cl] + sq[128+cl] + sq[192+cl];
    float m   = ts * (1.f / NB);
    float var = tq * (1.f / NB) - m*m;
    float inv = 1.f / sqrtf(var + 1e-5f);
    int e = c >> 10, j = c & 1023;
    float gg = bn_g[e*1024 + j], bb = bn_be[e*1024 + j];
    smul[cl] = gg * inv;
    sadd[cl] = bb - m * gg * inv;
  }
  __syncthreads();
  const float mu = smul[cl], ad = sadd[cl];
  for (int r = rg; r < NB; r += 4){
    size_t idx = (size_t)r * 7168;
    col[idx] = f2bf(bf2f(col[idx]) * mu + ad);
  }
}

// ---------------------------------------------------------------------------
// Row LayerNorm for ln0/ln1/shared slices of H, in place
// ---------------------------------------------------------------------------
__global__ __launch_bounds__(128) void k_ln(unsigned short* __restrict__ H,
    const float* __restrict__ ln_g, const float* __restrict__ ln_be,
    const float* __restrict__ sh_g, const float* __restrict__ sh_be){
  const int row = blockIdx.x, sl = blockIdx.y;
  unsigned short* p = H + (size_t)row * 7168 + 4096 + sl * 1024;
  const int t = threadIdx.x, lane = t & 63, w = t >> 6;
  short8v raw = *(const short8v*)&p[t * 8];
  float v[8]; float s = 0.f, s2 = 0.f;
  #pragma unroll
  for (int j = 0; j < 8; j++){ v[j] = bf2f((unsigned short)raw[j]); s += v[j]; s2 += v[j]*v[j]; }
  #pragma unroll
  for (int d = 1; d < 64; d <<= 1){ s += __shfl_xor(s, d); s2 += __shfl_xor(s2, d); }
  __shared__ float red[4];
  if (lane == 0){ red[w*2] = s; red[w*2+1] = s2; }
  __syncthreads();
  float ts = red[0] + red[2], tq = red[1] + red[3];
  float m   = ts * (1.f / 1024.f);
  float var = tq * (1.f / 1024.f) - m*m;
  float inv = 1.f / sqrtf(var + 1e-5f);
  const float* gp = (sl == 0) ? ln_g : (sl == 1) ? ln_g + 1024 : sh_g;
  const float* bp = (sl == 0) ? ln_be : (sl == 1) ? ln_be + 1024 : sh_be;
  short8v outv;
  #pragma unroll
  for (int j = 0; j < 8; j++){
    int cc = t*8 + j;
    outv[j] = (short)f2bf((v[j] - m) * inv * gp[cc] + bp[cc]);
  }
  *(short8v*)&p[t * 8] = outv;
}

// ---------------------------------------------------------------------------
// private = sum_e wgt[b][e] * expert_out[e][b,:]
// ---------------------------------------------------------------------------
__global__ __launch_bounds__(256) void k_combine(const unsigned short* __restrict__ eolin,
    const unsigned short* __restrict__ eoc, const float* __restrict__ wgt, float* __restrict__ priv){
  const int i = blockIdx.x * 256 + threadIdx.x;  // 524288
  const int b = i >> 7;
  const int c = (i & 127) * 8;
  const float* w = wgt + (size_t)b * 8;
  float acc[8];
  #pragma unroll
  for (int j = 0; j < 8; j++) acc[j] = 0.f;
  const int emap[6] = {0, 1, 2, 3, 6, 7};
  #pragma unroll
  for (int r = 0; r < 6; r++){
    float we = w[emap[r]];
    short8v v = *(const short8v*)&eolin[((size_t)r * NB + b) * 1024 + c];
    #pragma unroll
    for (int j = 0; j < 8; j++) acc[j] += we * bf2f((unsigned short)v[j]);
  }
  #pragma unroll
  for (int e2 = 0; e2 < 2; e2++){
    float we = w[4 + e2];
    short8v v = *(const short8v*)&eoc[((size_t)e2 * NB + b) * 1024 + c];
    #pragma unroll
    for (int j = 0; j < 8; j++) acc[j] += we * bf2f((unsigned short)v[j]);
  }
  float4v o0 = {acc[0], acc[1], acc[2], acc[3]};
  float4v o1 = {acc[4], acc[5], acc[6], acc[7]};
  float4v* dst = (float4v*)&priv[(size_t)b * 1024 + c];
  dst[0] = o0; dst[1] = o1;
}

// ---------------------------------------------------------------------------
// Host launch
// ---------------------------------------------------------------------------
extern "C" void kernel_launch(void* const* d_in, const int* in_sizes, int n_in,
                              void* d_out, int out_size, void* d_ws, size_t ws_size,
                              hipStream_t stream){
  const float* x      = (const float*)d_in[0];
  const int*   modal  = (const int*)d_in[1];
  const float* mlp_W1 = (const float*)d_in[2];
  const float* mlp_b1 = (const float*)d_in[3];
  const float* mlp_W2 = (const float*)d_in[4];
  const float* mlp_b2 = (const float*)d_in[5];
  const float* bn_W1  = (const float*)d_in[6];
  const float* bn_b1  = (const float*)d_in[7];
  const float* bn_g   = (const float*)d_in[8];
  const float* bn_be  = (const float*)d_in[9];
  const float* bn_W2  = (const float*)d_in[10];
  const float* bn_b2  = (const float*)d_in[11];
  const float* conv_k = (const float*)d_in[12];
  const float* conv_b = (const float*)d_in[13];
  const float* conv_W = (const float*)d_in[14];
  const float* conv_bL= (const float*)d_in[15];
  const float* ln_W1  = (const float*)d_in[16];
  const float* ln_b1  = (const float*)d_in[17];
  const float* ln_g   = (const float*)d_in[18];
  const float* ln_be  = (const float*)d_in[19];
  const float* ln_W2  = (const float*)d_in[20];
  const float* ln_b2  = (const float*)d_in[21];
  const float* sh_W1  = (const float*)d_in[22];
  const float* sh_b1  = (const float*)d_in[23];
  const float* sh_g   = (const float*)d_in[24];
  const float* sh_be  = (const float*)d_in[25];
  const float* sh_W2  = (const float*)d_in[26];
  const float* sh_b2  = (const float*)d_in[27];
  const float* g_W1   = (const float*)d_in[28];
  const float* g_b1   = (const float*)d_in[29];
  const float* g_W2   = (const float*)d_in[30];
  const float* g_b2   = (const float*)d_in[31];

  char* ws = (char*)d_ws;
  size_t o_xb   = 0;
  size_t o_xlo  = o_xb  + 8388608ull;
  size_t o_W1t  = o_xlo + 8388608ull;    // [9216][1024] bf16
  size_t o_W2t  = o_W1t + 18874368ull;   // [7168][1024] bf16
  size_t o_Wg   = o_W2t + 14680064ull;   // [512][3072] bf16
  size_t o_T    = o_Wg  + 3145728ull;    // [4096][512] f32
  size_t o_H    = o_T   + 8388608ull;    // [4096][7168] bf16
  size_t o_eoc  = o_H   + 58720256ull;   // [2][4096][1024] bf16
  size_t o_eol  = o_eoc + 16777216ull;   // [6][4096][1024] bf16
  size_t o_b1   = o_eol + 50331648ull;   // [9216] f32
  size_t o_b2   = o_b1  + 36864ull;      // [7168] f32
  size_t o_wgt  = o_b2  + 28672ull;      // [4096][8] f32
  size_t o_us   = o_wgt + 131072ull;     // [8] f64

  unsigned short* xb    = (unsigned short*)(ws + o_xb);
  unsigned short* xlo   = (unsigned short*)(ws + o_xlo);
  unsigned short* W1t   = (unsigned short*)(ws + o_W1t);
  unsigned short* W2t   = (unsigned short*)(ws + o_W2t);
  unsigned short* Wg3t  = (unsigned short*)(ws + o_Wg);
  float*          T     = (float*)(ws + o_T);
  unsigned short* H     = (unsigned short*)(ws + o_H);
  unsigned short* eoc   = (unsigned short*)(ws + o_eoc);
  unsigned short* eolin = (unsigned short*)(ws + o_eol);
  float*          b1cat = (float*)(ws + o_b1);
  float*          b2cat = (float*)(ws + o_b2);
  float*          wgt   = (float*)(ws + o_wgt);
  double*         usage = (double*)(ws + o_us);

  float* outF   = (float*)d_out;
  float* shared = outF;                       // [4096][1024]
  float* priv   = outF + (size_t)NB * 1024;   // [4096][1024]
  float* auxp   = outF + (size_t)2 * NB * 1024; // [1]

  hipMemsetAsync(usage, 0, 8 * sizeof(double), stream);

  k_cast_x<<<4096, 256, 0, stream>>>(x, xb, xlo);

  TpArgs tp;
  for (int e = 0; e < 2; e++){
    tp.src[0 + e] = mlp_W1 + (size_t)e * 1048576;
    tp.src[2 + e] = bn_W1  + (size_t)e * 1048576;
    tp.src[4 + e] = ln_W1  + (size_t)e * 1048576;
  }
  tp.src[6] = sh_W1;
  for (int e = 0; e < 2; e++){
    tp.src[7 + e]  = mlp_W2 + (size_t)e * 1048576;
    tp.src[9 + e]  = bn_W2  + (size_t)e * 1048576;
    tp.src[11 + e] = ln_W2  + (size_t)e * 1048576;
  }
  tp.src[13] = sh_W2;
  for (int s = 0; s < 7; s++)  tp.dst[s] = W1t + (size_t)s * 1048576;
  for (int s = 7; s < 14; s++) tp.dst[s] = W2t + (size_t)(s - 7) * 1048576;
  k_transpose<<<dim3(32, 32, 14), dim3(32, 8), 0, stream>>>(tp);

  k_gateW<<<dim3(32, 16), dim3(32, 8), 0, stream>>>(g_W1, Wg3t);
  k_convW<<<dim3(8, 2), 128, 0, stream>>>(conv_k, conv_b, conv_W, conv_bL, W1t, b1cat);
  k_biases<<<56, 256, 0, stream>>>(mlp_b1, bn_b1, ln_b1, sh_b1, mlp_b2, bn_b2, ln_b2, sh_b2, b1cat, b2cat);

  // ---- gate ----
  GemmArgs ga = {};
  ga.A = xb; ga.A2 = xlo; ga.Bt = Wg3t; ga.lda = 1024; ga.K = 3072;
  ga.bias = g_b1; ga.T = T; ga.w1last = g_W1 + (size_t)1024 * 512; ga.mod = modal;
  k_gemm<2><<<dim3(32, 4), 256, 0, stream>>>(ga);
  k_gate_fin<<<1024, 256, 0, stream>>>(T, g_W2, g_b2, wgt, usage);
  k_aux<<<1, 64, 0, stream>>>(usage, auxp);

  // ---- fused layer 1 (all first-layer GEMMs + conv experts) ----
  GemmArgs g1 = {};
  g1.A = xb; g1.Bt = W1t; g1.lda = 1024; g1.K = 1024;
  g1.bias = b1cat; g1.H = H; g1.eoc = eoc;
  k_gemm<0><<<dim3(32, 72), 256, 0, stream>>>(g1);

  k_bn<<<32, 256, 0, stream>>>(H, bn_g, bn_be);
  k_ln<<<dim3(4096, 3), 128, 0, stream>>>(H, ln_g, ln_be, sh_g, sh_be);

  // ---- fused layer 2 (6 private experts + shared) ----
  GemmArgs g2 = {};
  g2.A = H; g2.Bt = W2t; g2.lda = 7168; g2.K = 1024;
  g2.bias = b2cat; g2.eolin = eolin; g2.outsh = shared;
  k_gemm<1><<<dim3(32, 56), 256, 0, stream>>>(g2);

  k_combine<<<2048, 256, 0, stream>>>(eolin, eoc, wgt, priv);
}

// Round 2
// 645.182 us; speedup vs baseline: 2.7155x; 2.7155x over previous
//
#include <hip/hip_runtime.h>
#include <cstdint>
#include <cstddef>

// ---------------------------------------------------------------------------
// Problem constants (B=4096, DIN=DOUT=1024, E=8, K=4)
// ---------------------------------------------------------------------------
#define NB 4096
#define ND 1024

typedef __attribute__((ext_vector_type(8))) short short8v;
typedef __attribute__((ext_vector_type(4))) short short4v;
typedef __attribute__((ext_vector_type(4))) float float4v;

__device__ __forceinline__ unsigned short f2bf(float x){
  union{float f; unsigned u;} v; v.f = x;
  unsigned r = v.u + 0x7FFFu + ((v.u >> 16) & 1u);  // RNE
  return (unsigned short)(r >> 16);
}
__device__ __forceinline__ float bf2f(unsigned short h){
  union{unsigned u; float f;} v; v.u = ((unsigned)h) << 16; return v.f;
}

typedef const __attribute__((address_space(1))) unsigned int* gas_ptr;
typedef __attribute__((address_space(3))) unsigned int* las_ptr;

__device__ __forceinline__ void gload_lds16(const void* g, void* l){
  __builtin_amdgcn_global_load_lds((gas_ptr)g, (las_ptr)l, 16, 0, 0);
}

// ---------------------------------------------------------------------------
// Generic 128x128x(BK=32) bf16 MFMA GEMM, both operands [outer][K] layout.
// KIND 0: fused layer-1 (N=9216, epilogue per 1024-col region)
// KIND 1: fused layer-2 (N=7168, A col-offset per region)
// KIND 2: gate GEMM1 (N=512, K=3072 bf16x3 split, tanh epilogue -> T fp32)
// ---------------------------------------------------------------------------
struct GemmArgs {
  const unsigned short* A;     // bf16 [M][lda]
  const unsigned short* A2;    // xlo (gate only)
  const unsigned short* Bt;    // bf16 [N][K]
  int lda;
  int K;
  const float* bias;           // [N]
  unsigned short* H;           // KIND0 dest (cols 0..7167)
  unsigned short* eoc;         // KIND0 conv dest [2][4096][1024]
  unsigned short* eolin;       // KIND1 dest [6][4096][1024]
  float* outsh;                // KIND1 shared dest (d_out)
  float* T;                    // KIND2 dest [4096][512]
  const float* w1last;         // gate: g_W1 row 1024
  const int* mod;              // modality_id
};

template<int KIND>
__global__ __launch_bounds__(256, 2) void k_gemm(GemmArgs g){
  __shared__ unsigned short sA[128*32];
  __shared__ unsigned short sB[128*32];
  const int tid  = threadIdx.x;
  const int lane = tid & 63;
  const int wid  = tid >> 6;
  const int m0 = blockIdx.x * 128;
  const int n0 = blockIdx.y * 128;
  const int srow   = tid >> 2;        // 0..63
  const int schunk = (tid & 3) * 8;   // k element offset
  const int K   = g.K;
  const int lda = g.lda;

  const unsigned short* Abase0 = g.A + (KIND == 1 ? (size_t)(blockIdx.y >> 3) * 1024 : 0);

  unsigned short* lA0 = &sA[wid * 512];
  unsigned short* lA1 = &sA[2048 + wid * 512];
  unsigned short* lB0 = &sB[wid * 512];
  unsigned short* lB1 = &sB[2048 + wid * 512];

  const int wr = wid >> 1, wc = wid & 1;
  const int fr = lane & 15;
  const int kc = (lane >> 4) * 8;

  float4v acc[4][4];
  #pragma unroll
  for (int i = 0; i < 4; i++)
    #pragma unroll
    for (int j = 0; j < 4; j++) acc[i][j] = (float4v){0.f, 0.f, 0.f, 0.f};

  for (int k0 = 0; k0 < K; k0 += 32){
    const unsigned short* Ab; int acol;
    if (KIND == 2){ int seg = k0 >> 10; Ab = (seg == 1) ? g.A2 : g.A; acol = k0 & 1023; }
    else          { Ab = Abase0; acol = k0; }
    gload_lds16(Ab + (size_t)(m0      + srow) * lda + acol + schunk, lA0);
    gload_lds16(Ab + (size_t)(m0 + 64 + srow) * lda + acol + schunk, lA1);
    gload_lds16(g.Bt + (size_t)(n0      + srow) * K + k0 + schunk, lB0);
    gload_lds16(g.Bt + (size_t)(n0 + 64 + srow) * K + k0 + schunk, lB1);
    __syncthreads();
    short8v a[4], b[4];
    #pragma unroll
    for (int mi = 0; mi < 4; mi++) a[mi] = *(const short8v*)&sA[(wr*64 + mi*16 + fr)*32 + kc];
    #pragma unroll
    for (int ni = 0; ni < 4; ni++) b[ni] = *(const short8v*)&sB[(wc*64 + ni*16 + fr)*32 + kc];
    #pragma unroll
    for (int mi = 0; mi < 4; mi++)
      #pragma unroll
      for (int ni = 0; ni < 4; ni++)
        acc[mi][ni] = __builtin_amdgcn_mfma_f32_16x16x32_bf16(a[mi], b[ni], acc[mi][ni], 0, 0, 0);
    __syncthreads();
  }

  const int mr0 = m0 + wr * 64;
  const int nc0 = n0 + wc * 64;
  #pragma unroll
  for (int ni = 0; ni < 4; ni++){
    const int ncol = nc0 + ni * 16 + fr;
    const float bval = g.bias[ncol];
    #pragma unroll
    for (int mi = 0; mi < 4; mi++){
      const int mrow = mr0 + mi * 16 + (lane >> 4) * 4;
      float4v v = acc[mi][ni];
      #pragma unroll
      for (int r = 0; r < 4; r++){
        float val = v[r] + bval;
        const int m = mrow + r;
        if (KIND == 0){
          const int region = ncol >> 10;
          if (region < 7){
            float o;
            if (region < 2 || region == 6)      o = fmaxf(val, 0.f);           // relu (mlp, shared)
            else if (region < 4)                o = tanhf(val);                // bn experts
            else                                o = val * (1.f/(1.f+expf(-val))); // silu (ln experts)
            g.H[(size_t)m * 7168 + ncol] = f2bf(o);
          } else {
            float o = 0.5f * val * (1.f + erff(val * 0.70710678118654752f));   // exact gelu
            const int e = region - 7, cc = ncol & 1023;
            g.eoc[((size_t)e * NB + m) * 1024 + cc] = f2bf(o);
          }
        } else if (KIND == 1){
          const int region = ncol >> 10, cc = ncol & 1023;
          if (region < 6) g.eolin[((size_t)region * NB + m) * 1024 + cc] = f2bf(val);
          else            g.outsh[(size_t)m * 1024 + cc] = val;                // shared expert
        } else {
          float t = tanhf(val + (float)g.mod[m] * g.w1last[ncol]);
          g.T[(size_t)m * 512 + ncol] = t;
        }
      }
    }
  }
}

// ---------------------------------------------------------------------------
// Prep kernels
// ---------------------------------------------------------------------------
__global__ void k_cast_x(const float* __restrict__ x, unsigned short* __restrict__ xb,
                         unsigned short* __restrict__ xlo){
  int i = blockIdx.x * 256 + threadIdx.x;      // 1M threads, 4 elems each
  float4v v = ((const float4v*)x)[i];
  short4v hi, lo;
  #pragma unroll
  for (int j = 0; j < 4; j++){
    unsigned short h = f2bf(v[j]);
    hi[j] = (short)h;
    lo[j] = (short)f2bf(v[j] - bf2f(h));
  }
  ((short4v*)xb)[i]  = hi;
  ((short4v*)xlo)[i] = lo;
}

struct TpArgs { const float* src[14]; unsigned short* dst[14]; };

__global__ void k_transpose(TpArgs a){
  __shared__ float tile[32][33];
  const float* src = a.src[blockIdx.z];
  unsigned short* dst = a.dst[blockIdx.z];
  const int bx = blockIdx.x, by = blockIdx.y;   // bx: n-tile, by: k-tile
  const int tx = threadIdx.x, ty = threadIdx.y;
  #pragma unroll
  for (int i = 0; i < 32; i += 8)
    tile[ty + i][tx] = src[(size_t)(by*32 + ty + i) * 1024 + bx*32 + tx];
  __syncthreads();
  #pragma unroll
  for (int i = 0; i < 32; i += 8)
    dst[(size_t)(bx*32 + ty + i) * 1024 + by*32 + tx] = f2bf(tile[tx][ty + i]);
}

__global__ void k_gateW(const float* __restrict__ gW1, unsigned short* __restrict__ Wg3t){
  __shared__ float tile[32][33];
  const int bx = blockIdx.x, by = blockIdx.y;   // bx: k-tile(32), by: n-tile(16)
  const int tx = threadIdx.x, ty = threadIdx.y;
  #pragma unroll
  for (int i = 0; i < 32; i += 8)
    tile[ty + i][tx] = gW1[(size_t)(bx*32 + ty + i) * 512 + by*32 + tx];
  __syncthreads();
  #pragma unroll
  for (int i = 0; i < 32; i += 8){
    int n = by*32 + ty + i, k = bx*32 + tx;
    float v = tile[tx][ty + i];
    unsigned short hi = f2bf(v);
    unsigned short lo = f2bf(v - bf2f(hi));
    Wg3t[(size_t)n*3072 + k]        = hi;
    Wg3t[(size_t)n*3072 + 1024 + k] = hi;
    Wg3t[(size_t)n*3072 + 2048 + k] = lo;
  }
}

// conv1d+flatten+linear == linear with transformed weight.
// Chunked: grid (4 o-blocks, 32 ip-chunks, 2 experts) x 256 thr.
// Each thread rolls prev/cur/next over 32 ip values for its column o,
// writes 32 bf16 outputs as 4x short8v, atomicAdds partial colsums.
__global__ __launch_bounds__(256) void k_convW(const float* __restrict__ convk,
    const float* __restrict__ convW, unsigned short* __restrict__ W1t,
    float* __restrict__ scPart){
  const int e   = blockIdx.z;
  const int ip0 = blockIdx.y * 32;
  const int o   = blockIdx.x * 256 + threadIdx.x;
  const float* W = convW + (size_t)e * 4096 * 1024;
  float kk[4][3];
  #pragma unroll
  for (int c = 0; c < 4; c++)
    #pragma unroll
    for (int j = 0; j < 3; j++) kk[c][j] = convk[e*12 + c*3 + j];

  float wprev[4], wcur[4], sc[4];
  #pragma unroll
  for (int c = 0; c < 4; c++){
    wprev[c] = (ip0 > 0) ? W[(size_t)(c*1024 + ip0 - 1) * 1024 + o] : 0.f;
    wcur[c]  = W[(size_t)(c*1024 + ip0) * 1024 + o];
    sc[c] = 0.f;
  }
  short8v ov[4];
  #pragma unroll
  for (int i = 0; i < 32; i++){
    const int ip = ip0 + i;
    float wnext[4];
    #pragma unroll
    for (int c = 0; c < 4; c++)
      wnext[c] = (ip < 1023) ? W[(size_t)(c*1024 + ip + 1) * 1024 + o] : 0.f;
    float acc = 0.f;
    #pragma unroll
    for (int c = 0; c < 4; c++){
      acc += kk[c][0]*wnext[c] + kk[c][1]*wcur[c] + kk[c][2]*wprev[c];
      sc[c] += wcur[c];
    }
    ov[i >> 3][i & 7] = (short)f2bf(acc);
    #pragma unroll
    for (int c = 0; c < 4; c++){ wprev[c] = wcur[c]; wcur[c] = wnext[c]; }
  }
  unsigned short* drow = W1t + (size_t)(7168 + e*1024 + o) * 1024;
  #pragma unroll
  for (int q = 0; q < 4; q++) *(short8v*)&drow[ip0 + q*8] = ov[q];
  #pragma unroll
  for (int c = 0; c < 4; c++) atomicAdd(&scPart[(e*4 + c)*1024 + o], sc[c]);
}

__global__ void k_conv_bias(const float* __restrict__ convb, const float* __restrict__ convbL,
                            const float* __restrict__ scPart, float* __restrict__ b1cat){
  const int i = blockIdx.x * 256 + threadIdx.x;   // 2048
  const int e = i >> 10, o = i & 1023;
  float b = convbL[i];
  #pragma unroll
  for (int c = 0; c < 4; c++) b += convb[e*4 + c] * scPart[(e*4 + c)*1024 + o];
  b1cat[7168 + i] = b;
}

__global__ void k_biases(const float* mlp_b1, const float* bn_b1, const float* ln_b1, const float* sh_b1,
                         const float* mlp_b2, const float* bn_b2, const float* ln_b2, const float* sh_b2,
                         float* b1cat, float* b2cat){
  int i = blockIdx.x * 256 + threadIdx.x;   // 14336
  if (i < 7168){
    int r = i >> 10;
    float v;
    if (r < 2) v = mlp_b1[i];
    else if (r < 4) v = bn_b1[i - 2048];
    else if (r < 6) v = ln_b1[i - 4096];
    else v = sh_b1[i - 6144];
    b1cat[i] = v;
  } else {
    int j = i - 7168;
    int r = j >> 10;
    float v;
    if (r < 2) v = mlp_b2[j];
    else if (r < 4) v = bn_b2[j - 2048];
    else if (r < 6) v = ln_b2[j - 4096];
    else v = sh_b2[j - 6144];
    b2cat[j] = v;
  }
}

// ---------------------------------------------------------------------------
// Gate finalize: fp32 logits GEMM2 (512x8), clip, top-4, softmax weights.
// Per-token usage probs written to usageTok; reduced deterministically in k_aux.
// ---------------------------------------------------------------------------
__global__ __launch_bounds__(256) void k_gate_fin(const float* __restrict__ T, const float* __restrict__ gW2,
                                                  const float* __restrict__ gb2,
                                                  float* __restrict__ wgt, float* __restrict__ usageTok){
  const int tok  = blockIdx.x * 4 + (threadIdx.x >> 6);
  const int lane = threadIdx.x & 63;
  const int e = lane >> 3, sub = lane & 7;
  const float* tr = T + (size_t)tok * 512;
  float p = 0.f;
  for (int k = sub; k < 512; k += 8) p += tr[k] * gW2[k*8 + e];
  p += __shfl_xor(p, 1); p += __shfl_xor(p, 2); p += __shfl_xor(p, 4);
  float le[8];
  #pragma unroll
  for (int q = 0; q < 8; q++) le[q] = __shfl(p, q * 8);
  #pragma unroll
  for (int q = 0; q < 8; q++){
    float l = (le[q] + gb2[q]) / 0.7f;
    le[q] = fminf(fmaxf(l, -10.f), 10.f);
  }
  unsigned sel = 0; int idx4[4]; float bv4[4];
  #pragma unroll
  for (int t4 = 0; t4 < 4; t4++){
    float best = -1e30f; int bi = 0;
    for (int q = 0; q < 8; q++)
      if (!((sel >> q) & 1u) && le[q] > best){ best = le[q]; bi = q; }
    sel |= 1u << bi; idx4[t4] = bi; bv4[t4] = best;
  }
  const float mx = bv4[0];                 // global max
  float s4 = 0.f, w4[4];
  #pragma unroll
  for (int t4 = 0; t4 < 4; t4++){ w4[t4] = expf(bv4[t4] - mx); s4 += w4[t4]; }
  float su = 0.f, us[8];
  #pragma unroll
  for (int q = 0; q < 8; q++){ us[q] = expf(le[q] - mx); su += us[q]; }
  if (lane == 0){
    float wr[8] = {0,0,0,0,0,0,0,0};
    #pragma unroll
    for (int t4 = 0; t4 < 4; t4++) wr[idx4[t4]] = w4[t4] / s4;
    const float inv = 1.f / su;
    #pragma unroll
    for (int q = 0; q < 8; q++) wgt[(size_t)tok*8 + q] = wr[q];
    #pragma unroll
    for (int q = 0; q < 8; q++) usageTok[(size_t)tok*8 + q] = us[q] * inv;
  }
}

__global__ __launch_bounds__(256) void k_aux(const float* __restrict__ usageTok, float* __restrict__ auxp){
  __shared__ float red[256][8];
  float a[8] = {0,0,0,0,0,0,0,0};
  for (int r = threadIdx.x; r < NB; r += 256){
    float4v v0 = *(const float4v*)&usageTok[(size_t)r * 8];
    float4v v1 = *(const float4v*)&usageTok[(size_t)r * 8 + 4];
    #pragma unroll
    for (int j = 0; j < 4; j++){ a[j] += v0[j]; a[4+j] += v1[j]; }
  }
  #pragma unroll
  for (int q = 0; q < 8; q++) red[threadIdx.x][q] = a[q];
  __syncthreads();
  if (threadIdx.x == 0){
    float s[8] = {0,0,0,0,0,0,0,0};
    for (int t = 0; t < 256; t++)
      #pragma unroll
      for (int q = 0; q < 8; q++) s[q] += red[t][q];
    float acc = 0.f;
    for (int q = 0; q < 8; q++){
      float u = s[q] * (1.f / 4096.f);
      acc += 0.125f * (-2.0794415f - logf(u + 1e-10f));
    }
    auxp[0] = acc * 0.125f;
  }
}

// ---------------------------------------------------------------------------
// BatchNorm (batch stats) over H cols 2048..4095: 2-pass, row-major coalesced.
// ---------------------------------------------------------------------------
__global__ __launch_bounds__(256) void k_bn_stats(const unsigned short* __restrict__ H,
                                                  float* __restrict__ colstats){
  const int r0 = blockIdx.x * 64;
  const int c0 = threadIdx.x * 8;
  float s[8], s2[8];
  #pragma unroll
  for (int j = 0; j < 8; j++){ s[j] = 0.f; s2[j] = 0.f; }
  for (int r = 0; r < 64; r++){
    short8v v = *(const short8v*)&H[(size_t)(r0 + r) * 7168 + 2048 + c0];
    #pragma unroll
    for (int j = 0; j < 8; j++){
      float f = bf2f((unsigned short)v[j]);
      s[j] += f; s2[j] += f * f;
    }
  }
  #pragma unroll
  for (int j = 0; j < 8; j++){
    atomicAdd(&colstats[c0 + j], s[j]);
    atomicAdd(&colstats[2048 + c0 + j], s2[j]);
  }
}

__global__ __launch_bounds__(256) void k_bn_apply(unsigned short* __restrict__ H,
    const float* __restrict__ colstats,
    const float* __restrict__ bn_g, const float* __restrict__ bn_be){
  const int r0 = blockIdx.x * 16;
  const int c0 = threadIdx.x * 8;
  float mul[8], add[8];
  #pragma unroll
  for (int j = 0; j < 8; j++){
    const int c = c0 + j;
    float m   = colstats[c] * (1.f / NB);
    float var = colstats[2048 + c] * (1.f / NB) - m * m;
    float inv = 1.f / sqrtf(var + 1e-5f);
    const int e = c >> 10, cc = c & 1023;
    float g = bn_g[e*1024 + cc], b = bn_be[e*1024 + cc];
    mul[j] = g * inv;
    add[j] = b - m * g * inv;
  }
  for (int r = 0; r < 16; r++){
    unsigned short* p = &H[(size_t)(r0 + r) * 7168 + 2048 + c0];
    short8v v = *(const short8v*)p;
    short8v o;
    #pragma unroll
    for (int j = 0; j < 8; j++)
      o[j] = (short)f2bf(bf2f((unsigned short)v[j]) * mul[j] + add[j]);
    *(short8v*)p = o;
  }
}

// ---------------------------------------------------------------------------
// Row LayerNorm for ln0/ln1/shared slices of H, in place
// ---------------------------------------------------------------------------
__global__ __launch_bounds__(128) void k_ln(unsigned short* __restrict__ H,
    const float* __restrict__ ln_g, const float* __restrict__ ln_be,
    const float* __restrict__ sh_g, const float* __restrict__ sh_be){
  const int row = blockIdx.x, sl = blockIdx.y;
  unsigned short* p = H + (size_t)row * 7168 + 4096 + sl * 1024;
  const int t = threadIdx.x, lane = t & 63, w = t >> 6;
  short8v raw = *(const short8v*)&p[t * 8];
  float v[8]; float s = 0.f, s2 = 0.f;
  #pragma unroll
  for (int j = 0; j < 8; j++){ v[j] = bf2f((unsigned short)raw[j]); s += v[j]; s2 += v[j]*v[j]; }
  #pragma unroll
  for (int d = 1; d < 64; d <<= 1){ s += __shfl_xor(s, d); s2 += __shfl_xor(s2, d); }
  __shared__ float red[4];
  if (lane == 0){ red[w*2] = s; red[w*2+1] = s2; }
  __syncthreads();
  float ts = red[0] + red[2], tq = red[1] + red[3];
  float m   = ts * (1.f / 1024.f);
  float var = tq * (1.f / 1024.f) - m*m;
  float inv = 1.f / sqrtf(var + 1e-5f);
  const float* gp = (sl == 0) ? ln_g : (sl == 1) ? ln_g + 1024 : sh_g;
  const float* bp = (sl == 0) ? ln_be : (sl == 1) ? ln_be + 1024 : sh_be;
  short8v outv;
  #pragma unroll
  for (int j = 0; j < 8; j++){
    int cc = t*8 + j;
    outv[j] = (short)f2bf((v[j] - m) * inv * gp[cc] + bp[cc]);
  }
  *(short8v*)&p[t * 8] = outv;
}

// ---------------------------------------------------------------------------
// private = sum_e wgt[b][e] * expert_out[e][b,:]
// ---------------------------------------------------------------------------
__global__ __launch_bounds__(256) void k_combine(const unsigned short* __restrict__ eolin,
    const unsigned short* __restrict__ eoc, const float* __restrict__ wgt, float* __restrict__ priv){
  const int i = blockIdx.x * 256 + threadIdx.x;  // 524288
  const int b = i >> 7;
  const int c = (i & 127) * 8;
  const float* w = wgt + (size_t)b * 8;
  float acc[8];
  #pragma unroll
  for (int j = 0; j < 8; j++) acc[j] = 0.f;
  const int emap[6] = {0, 1, 2, 3, 6, 7};
  #pragma unroll
  for (int r = 0; r < 6; r++){
    float we = w[emap[r]];
    short8v v = *(const short8v*)&eolin[((size_t)r * NB + b) * 1024 + c];
    #pragma unroll
    for (int j = 0; j < 8; j++) acc[j] += we * bf2f((unsigned short)v[j]);
  }
  #pragma unroll
  for (int e2 = 0; e2 < 2; e2++){
    float we = w[4 + e2];
    short8v v = *(const short8v*)&eoc[((size_t)e2 * NB + b) * 1024 + c];
    #pragma unroll
    for (int j = 0; j < 8; j++) acc[j] += we * bf2f((unsigned short)v[j]);
  }
  float4v o0 = {acc[0], acc[1], acc[2], acc[3]};
  float4v o1 = {acc[4], acc[5], acc[6], acc[7]};
  float4v* dst = (float4v*)&priv[(size_t)b * 1024 + c];
  dst[0] = o0; dst[1] = o1;
}

// ---------------------------------------------------------------------------
// Host launch
// ---------------------------------------------------------------------------
extern "C" void kernel_launch(void* const* d_in, const int* in_sizes, int n_in,
                              void* d_out, int out_size, void* d_ws, size_t ws_size,
                              hipStream_t stream){
  const float* x      = (const float*)d_in[0];
  const int*   modal  = (const int*)d_in[1];
  const float* mlp_W1 = (const float*)d_in[2];
  const float* mlp_b1 = (const float*)d_in[3];
  const float* mlp_W2 = (const float*)d_in[4];
  const float* mlp_b2 = (const float*)d_in[5];
  const float* bn_W1  = (const float*)d_in[6];
  const float* bn_b1  = (const float*)d_in[7];
  const float* bn_g   = (const float*)d_in[8];
  const float* bn_be  = (const float*)d_in[9];
  const float* bn_W2  = (const float*)d_in[10];
  const float* bn_b2  = (const float*)d_in[11];
  const float* conv_k = (const float*)d_in[12];
  const float* conv_b = (const float*)d_in[13];
  const float* conv_W = (const float*)d_in[14];
  const float* conv_bL= (const float*)d_in[15];
  const float* ln_W1  = (const float*)d_in[16];
  const float* ln_b1  = (const float*)d_in[17];
  const float* ln_g   = (const float*)d_in[18];
  const float* ln_be  = (const float*)d_in[19];
  const float* ln_W2  = (const float*)d_in[20];
  const float* ln_b2  = (const float*)d_in[21];
  const float* sh_W1  = (const float*)d_in[22];
  const float* sh_b1  = (const float*)d_in[23];
  const float* sh_g   = (const float*)d_in[24];
  const float* sh_be  = (const float*)d_in[25];
  const float* sh_W2  = (const float*)d_in[26];
  const float* sh_b2  = (const float*)d_in[27];
  const float* g_W1   = (const float*)d_in[28];
  const float* g_b1   = (const float*)d_in[29];
  const float* g_W2   = (const float*)d_in[30];
  const float* g_b2   = (const float*)d_in[31];

  char* ws = (char*)d_ws;
  size_t o_xb   = 0;
  size_t o_xlo  = o_xb  + 8388608ull;
  size_t o_W1t  = o_xlo + 8388608ull;    // [9216][1024] bf16
  size_t o_W2t  = o_W1t + 18874368ull;   // [7168][1024] bf16
  size_t o_Wg   = o_W2t + 14680064ull;   // [512][3072] bf16
  size_t o_T    = o_Wg  + 3145728ull;    // [4096][512] f32
  size_t o_H    = o_T   + 8388608ull;    // [4096][7168] bf16
  size_t o_eoc  = o_H   + 58720256ull;   // [2][4096][1024] bf16
  size_t o_eol  = o_eoc + 16777216ull;   // [6][4096][1024] bf16
  size_t o_b1   = o_eol + 50331648ull;   // [9216] f32
  size_t o_b2   = o_b1  + 36864ull;      // [7168] f32
  size_t o_wgt  = o_b2  + 28672ull;      // [4096][8] f32
  size_t o_ut   = o_wgt + 131072ull;     // [4096][8] f32 usage probs
  size_t o_scp  = o_ut  + 131072ull;     // [2][4][1024] f32 conv colsum partials
  size_t o_cst  = o_scp + 32768ull;      // [2][2048] f32 bn colstats

  unsigned short* xb    = (unsigned short*)(ws + o_xb);
  unsigned short* xlo   = (unsigned short*)(ws + o_xlo);
  unsigned short* W1t   = (unsigned short*)(ws + o_W1t);
  unsigned short* W2t   = (unsigned short*)(ws + o_W2t);
  unsigned short* Wg3t  = (unsigned short*)(ws + o_Wg);
  float*          T     = (float*)(ws + o_T);
  unsigned short* H     = (unsigned short*)(ws + o_H);
  unsigned short* eoc   = (unsigned short*)(ws + o_eoc);
  unsigned short* eolin = (unsigned short*)(ws + o_eol);
  float*          b1cat = (float*)(ws + o_b1);
  float*          b2cat = (float*)(ws + o_b2);
  float*          wgt   = (float*)(ws + o_wgt);
  float*          usageTok = (float*)(ws + o_ut);
  float*          scPart   = (float*)(ws + o_scp);
  float*          colstats = (float*)(ws + o_cst);

  float* outF   = (float*)d_out;
  float* shared = outF;                       // [4096][1024]
  float* priv   = outF + (size_t)NB * 1024;   // [4096][1024]
  float* auxp   = outF + (size_t)2 * NB * 1024; // [1]

  hipMemsetAsync(scPart, 0, 32768, stream);
  hipMemsetAsync(colstats, 0, 16384, stream);

  k_cast_x<<<4096, 256, 0, stream>>>(x, xb, xlo);

  TpArgs tp;
  for (int e = 0; e < 2; e++){
    tp.src[0 + e] = mlp_W1 + (size_t)e * 1048576;
    tp.src[2 + e] = bn_W1  + (size_t)e * 1048576;
    tp.src[4 + e] = ln_W1  + (size_t)e * 1048576;
  }
  tp.src[6] = sh_W1;
  for (int e = 0; e < 2; e++){
    tp.src[7 + e]  = mlp_W2 + (size_t)e * 1048576;
    tp.src[9 + e]  = bn_W2  + (size_t)e * 1048576;
    tp.src[11 + e] = ln_W2  + (size_t)e * 1048576;
  }
  tp.src[13] = sh_W2;
  for (int s = 0; s < 7; s++)  tp.dst[s] = W1t + (size_t)s * 1048576;
  for (int s = 7; s < 14; s++) tp.dst[s] = W2t + (size_t)(s - 7) * 1048576;
  k_transpose<<<dim3(32, 32, 14), dim3(32, 8), 0, stream>>>(tp);

  k_gateW<<<dim3(32, 16), dim3(32, 8), 0, stream>>>(g_W1, Wg3t);
  k_convW<<<dim3(4, 32, 2), 256, 0, stream>>>(conv_k, conv_W, W1t, scPart);
  k_conv_bias<<<8, 256, 0, stream>>>(conv_b, conv_bL, scPart, b1cat);
  k_biases<<<56, 256, 0, stream>>>(mlp_b1, bn_b1, ln_b1, sh_b1, mlp_b2, bn_b2, ln_b2, sh_b2, b1cat, b2cat);

  // ---- gate ----
  GemmArgs ga = {};
  ga.A = xb; ga.A2 = xlo; ga.Bt = Wg3t; ga.lda = 1024; ga.K = 3072;
  ga.bias = g_b1; ga.T = T; ga.w1last = g_W1 + (size_t)1024 * 512; ga.mod = modal;
  k_gemm<2><<<dim3(32, 4), 256, 0, stream>>>(ga);
  k_gate_fin<<<1024, 256, 0, stream>>>(T, g_W2, g_b2, wgt, usageTok);
  k_aux<<<1, 256, 0, stream>>>(usageTok, auxp);

  // ---- fused layer 1 (all first-layer GEMMs + conv experts) ----
  GemmArgs g1 = {};
  g1.A = xb; g1.Bt = W1t; g1.lda = 1024; g1.K = 1024;
  g1.bias = b1cat; g1.H = H; g1.eoc = eoc;
  k_gemm<0><<<dim3(32, 72), 256, 0, stream>>>(g1);

  k_bn_stats<<<64, 256, 0, stream>>>(H, colstats);
  k_bn_apply<<<256, 256, 0, stream>>>(H, colstats, bn_g, bn_be);
  k_ln<<<dim3(4096, 3), 128, 0, stream>>>(H, ln_g, ln_be, sh_g, sh_be);

  // ---- fused layer 2 (6 private experts + shared) ----
  GemmArgs g2 = {};
  g2.A = H; g2.Bt = W2t; g2.lda = 7168; g2.K = 1024;
  g2.bias = b2cat; g2.eolin = eolin; g2.outsh = shared;
  k_gemm<1><<<dim3(32, 56), 256, 0, stream>>>(g2);

  k_combine<<<2048, 256, 0, stream>>>(eolin, eoc, wgt, priv);
}

// Round 3
// 549.091 us; speedup vs baseline: 3.1907x; 1.1750x over previous
//
#include <hip/hip_runtime.h>
#include <cstdint>
#include <cstddef>

// ---------------------------------------------------------------------------
// Problem constants (B=4096, DIN=DOUT=1024, E=8, K=4)
// ---------------------------------------------------------------------------
#define NB 4096
#define ND 1024

typedef __attribute__((ext_vector_type(8))) short short8v;
typedef __attribute__((ext_vector_type(4))) short short4v;
typedef __attribute__((ext_vector_type(4))) float float4v;

__device__ __forceinline__ unsigned short f2bf(float x){
  union{float f; unsigned u;} v; v.f = x;
  unsigned r = v.u + 0x7FFFu + ((v.u >> 16) & 1u);  // RNE
  return (unsigned short)(r >> 16);
}
__device__ __forceinline__ float bf2f(unsigned short h){
  union{unsigned u; float f;} v; v.u = ((unsigned)h) << 16; return v.f;
}

// fast activations (err ~1e-7, well under bf16 eps)
__device__ __forceinline__ float fast_tanh(float x){
  float xc = fminf(fmaxf(x, -15.f), 15.f);
  float e2 = __expf(2.f * xc);
  return 1.f - 2.f / (e2 + 1.f);
}
__device__ __forceinline__ float fast_silu(float x){
  return x / (1.f + __expf(-x));
}
__device__ __forceinline__ float fast_gelu(float x){
  // exact gelu with Abramowitz-Stegun 7.1.26 erf (|err| <= 1.5e-7)
  float a = fabsf(x) * 0.70710678118654752f;
  float t = 1.f / (1.f + 0.3275911f * a);
  float poly = t * (0.254829592f + t * (-0.284496736f + t * (1.421413741f +
               t * (-1.453152027f + t * 1.061405429f))));
  float erf = 1.f - poly * __expf(-a * a);
  erf = (x < 0.f) ? -erf : erf;
  return 0.5f * x * (1.f + erf);
}

typedef const __attribute__((address_space(1))) unsigned int* gas_ptr;
typedef __attribute__((address_space(3))) unsigned int* las_ptr;

__device__ __forceinline__ void gload_lds16(const void* g, void* l){
  __builtin_amdgcn_global_load_lds((gas_ptr)g, (las_ptr)l, 16, 0, 0);
}

// ---------------------------------------------------------------------------
// Generic 128x128x(BK=32) bf16 MFMA GEMM, both operands [outer][K] layout.
// KIND 0: fused layer-1 (N=9216, block-uniform activation epilogue via LDS)
// KIND 1: fused layer-2 (N=7168, A col-offset per region; region 6 = fp32 out)
// KIND 2: gate GEMM1 (N=512, K=3072 bf16x3 split, K-split x2, raw fp32 out)
// ---------------------------------------------------------------------------
struct GemmArgs {
  const unsigned short* A;     // bf16 [M][lda]
  const unsigned short* A2;    // xlo (gate only)
  const unsigned short* Bt;    // bf16 [N][K]
  int lda;
  int K;
  const float* bias;           // [N]
  unsigned short* H;           // KIND0 dest (cols 0..7167)
  unsigned short* eoc;         // KIND0 conv dest [2][4096][1024]
  unsigned short* eolin;       // KIND1 dest [6][4096][1024]
  float* outsh;                // KIND1 shared dest (d_out)
  float* T;                    // KIND2 dest [2][4096][512] raw partials
};

template<int KIND>
__global__ __launch_bounds__(256, 2) void k_gemm(GemmArgs g){
  constexpr int SMEM_SHORTS = (KIND == 2) ? 8192 : 16384;
  __shared__ unsigned short smem[SMEM_SHORTS];
  unsigned short* sA = smem;
  unsigned short* sB = smem + 4096;

  const int tid  = threadIdx.x;
  const int lane = tid & 63;
  const int wid  = tid >> 6;
  const int m0 = blockIdx.x * 128;
  const int n0 = blockIdx.y * 128;
  const int srow   = tid >> 2;        // 0..63
  const int schunk = (tid & 3) * 8;   // k element offset
  const int K   = g.K;
  const int lda = g.lda;
  const int region = n0 >> 10;        // block-uniform (tiles 128-aligned, regions 1024-aligned)

  const unsigned short* Abase0 = g.A + (KIND == 1 ? (size_t)region * 1024 : 0);

  unsigned short* lA0 = &sA[wid * 512];
  unsigned short* lA1 = &sA[2048 + wid * 512];
  unsigned short* lB0 = &sB[wid * 512];
  unsigned short* lB1 = &sB[2048 + wid * 512];

  const int wr = wid >> 1, wc = wid & 1;
  const int fr = lane & 15;
  const int kc = (lane >> 4) * 8;

  float4v acc[4][4];
  #pragma unroll
  for (int i = 0; i < 4; i++)
    #pragma unroll
    for (int j = 0; j < 4; j++) acc[i][j] = (float4v){0.f, 0.f, 0.f, 0.f};

  const int kbeg = (KIND == 2) ? blockIdx.z * 1536 : 0;
  const int kend = (KIND == 2) ? kbeg + 1536 : K;

  for (int k0 = kbeg; k0 < kend; k0 += 32){
    const unsigned short* Ab; int acol;
    if (KIND == 2){ int seg = k0 >> 10; Ab = (seg == 1) ? g.A2 : g.A; acol = k0 & 1023; }
    else          { Ab = Abase0; acol = k0; }
    gload_lds16(Ab + (size_t)(m0      + srow) * lda + acol + schunk, lA0);
    gload_lds16(Ab + (size_t)(m0 + 64 + srow) * lda + acol + schunk, lA1);
    gload_lds16(g.Bt + (size_t)(n0      + srow) * K + k0 + schunk, lB0);
    gload_lds16(g.Bt + (size_t)(n0 + 64 + srow) * K + k0 + schunk, lB1);
    __syncthreads();
    short8v a[4], b[4];
    #pragma unroll
    for (int mi = 0; mi < 4; mi++) a[mi] = *(const short8v*)&sA[(wr*64 + mi*16 + fr)*32 + kc];
    #pragma unroll
    for (int ni = 0; ni < 4; ni++) b[ni] = *(const short8v*)&sB[(wc*64 + ni*16 + fr)*32 + kc];
    #pragma unroll
    for (int mi = 0; mi < 4; mi++)
      #pragma unroll
      for (int ni = 0; ni < 4; ni++)
        acc[mi][ni] = __builtin_amdgcn_mfma_f32_16x16x32_bf16(a[mi], b[ni], acc[mi][ni], 0, 0, 0);
    __syncthreads();
  }

  // ------------------------- epilogue -------------------------
  if (KIND == 2){
    // raw fp32 partial (bias/tanh/mod applied in k_gate_fin)
    const int mr0 = m0 + wr * 64;
    const int nc0 = n0 + wc * 64;
    #pragma unroll
    for (int ni = 0; ni < 4; ni++){
      const int ncol = nc0 + ni * 16 + fr;
      #pragma unroll
      for (int mi = 0; mi < 4; mi++){
        const int mrow = mr0 + mi * 16 + (lane >> 4) * 4;
        float4v v = acc[mi][ni];
        #pragma unroll
        for (int r = 0; r < 4; r++)
          g.T[((size_t)blockIdx.z * NB + mrow + r) * 512 + ncol] = v[r];
      }
    }
  } else if (KIND == 1 && region == 6){
    // shared expert: direct fp32 (16 lanes x 4B = 64B coalesced runs)
    const int mr0 = m0 + wr * 64;
    const int nc0 = n0 + wc * 64;
    #pragma unroll
    for (int ni = 0; ni < 4; ni++){
      const int ncol = nc0 + ni * 16 + fr;
      const float bval = g.bias[ncol];
      #pragma unroll
      for (int mi = 0; mi < 4; mi++){
        const int mrow = mr0 + mi * 16 + (lane >> 4) * 4;
        float4v v = acc[mi][ni];
        #pragma unroll
        for (int r = 0; r < 4; r++)
          g.outsh[(size_t)(mrow + r) * 1024 + (ncol & 1023)] = v[r] + bval;
      }
    }
  } else {
    // stage activated bf16 tile into 32KB LDS (16B-chunk XOR swizzle), then
    // write 256B fully-coalesced rows.
    unsigned short* sC = smem;
    #pragma unroll
    for (int ni = 0; ni < 4; ni++){
      const int lc = wc * 64 + ni * 16 + fr;
      const float bval = g.bias[n0 + lc];
      #pragma unroll
      for (int mi = 0; mi < 4; mi++){
        const int lr0 = wr * 64 + mi * 16 + (lane >> 4) * 4;
        float4v v = acc[mi][ni];
        #pragma unroll
        for (int r = 0; r < 4; r++){
          float val = v[r] + bval;
          float o;
          if (KIND == 0){
            if (region < 2 || region == 6)      o = fmaxf(val, 0.f);   // relu
            else if (region < 4)                o = fast_tanh(val);    // bn experts
            else if (region < 6)                o = fast_silu(val);    // ln experts
            else                                o = fast_gelu(val);    // conv experts
          } else {
            o = val;                                                    // layer-2 linear
          }
          const int lr = lr0 + r;
          const int byteoff = lr * 256 + ((lc * 2) ^ ((lr & 7) << 4));
          *(unsigned short*)((char*)sC + byteoff) = f2bf(o);
        }
      }
    }
    __syncthreads();
    const int ct = tid & 15;   // 16B chunk within row
    const int rb = tid >> 4;   // 0..15
    #pragma unroll
    for (int p = 0; p < 8; p++){
      const int lr = rb + p * 16;
      const int m = m0 + lr;
      const int byteoff = lr * 256 + ((ct * 16) ^ ((lr & 7) << 4));
      short8v vv = *(const short8v*)((char*)sC + byteoff);
      unsigned short* dst;
      if (KIND == 0){
        if (region < 7) dst = g.H + (size_t)m * 7168 + n0 + ct * 8;
        else            dst = g.eoc + ((size_t)(region - 7) * NB + m) * 1024 + (n0 & 1023) + ct * 8;
      } else {
        dst = g.eolin + ((size_t)region * NB + m) * 1024 + (n0 & 1023) + ct * 8;
      }
      *(short8v*)dst = vv;
    }
  }
}

// ---------------------------------------------------------------------------
// Prep kernels
// ---------------------------------------------------------------------------
__global__ void k_cast_x(const float* __restrict__ x, unsigned short* __restrict__ xb,
                         unsigned short* __restrict__ xlo){
  int i = blockIdx.x * 256 + threadIdx.x;      // 1M threads, 4 elems each
  float4v v = ((const float4v*)x)[i];
  short4v hi, lo;
  #pragma unroll
  for (int j = 0; j < 4; j++){
    unsigned short h = f2bf(v[j]);
    hi[j] = (short)h;
    lo[j] = (short)f2bf(v[j] - bf2f(h));
  }
  ((short4v*)xb)[i]  = hi;
  ((short4v*)xlo)[i] = lo;
}

struct TpArgs { const float* src[14]; unsigned short* dst[14]; };

__global__ void k_transpose(TpArgs a){
  __shared__ float tile[32][33];
  const float* src = a.src[blockIdx.z];
  unsigned short* dst = a.dst[blockIdx.z];
  const int bx = blockIdx.x, by = blockIdx.y;   // bx: n-tile, by: k-tile
  const int tx = threadIdx.x, ty = threadIdx.y;
  #pragma unroll
  for (int i = 0; i < 32; i += 8)
    tile[ty + i][tx] = src[(size_t)(by*32 + ty + i) * 1024 + bx*32 + tx];
  __syncthreads();
  #pragma unroll
  for (int i = 0; i < 32; i += 8)
    dst[(size_t)(bx*32 + ty + i) * 1024 + by*32 + tx] = f2bf(tile[tx][ty + i]);
}

__global__ void k_gateW(const float* __restrict__ gW1, unsigned short* __restrict__ Wg3t){
  __shared__ float tile[32][33];
  const int bx = blockIdx.x, by = blockIdx.y;   // bx: k-tile(32), by: n-tile(16)
  const int tx = threadIdx.x, ty = threadIdx.y;
  #pragma unroll
  for (int i = 0; i < 32; i += 8)
    tile[ty + i][tx] = gW1[(size_t)(bx*32 + ty + i) * 512 + by*32 + tx];
  __syncthreads();
  #pragma unroll
  for (int i = 0; i < 32; i += 8){
    int n = by*32 + ty + i, k = bx*32 + tx;
    float v = tile[tx][ty + i];
    unsigned short hi = f2bf(v);
    unsigned short lo = f2bf(v - bf2f(hi));
    Wg3t[(size_t)n*3072 + k]        = hi;
    Wg3t[(size_t)n*3072 + 1024 + k] = hi;
    Wg3t[(size_t)n*3072 + 2048 + k] = lo;
  }
}

// conv1d+flatten+linear == linear with transformed weight.
__global__ __launch_bounds__(256) void k_convW(const float* __restrict__ convk,
    const float* __restrict__ convW, unsigned short* __restrict__ W1t,
    float* __restrict__ scPart){
  const int e   = blockIdx.z;
  const int ip0 = blockIdx.y * 32;
  const int o   = blockIdx.x * 256 + threadIdx.x;
  const float* W = convW + (size_t)e * 4096 * 1024;
  float kk[4][3];
  #pragma unroll
  for (int c = 0; c < 4; c++)
    #pragma unroll
    for (int j = 0; j < 3; j++) kk[c][j] = convk[e*12 + c*3 + j];

  float wprev[4], wcur[4], sc[4];
  #pragma unroll
  for (int c = 0; c < 4; c++){
    wprev[c] = (ip0 > 0) ? W[(size_t)(c*1024 + ip0 - 1) * 1024 + o] : 0.f;
    wcur[c]  = W[(size_t)(c*1024 + ip0) * 1024 + o];
    sc[c] = 0.f;
  }
  short8v ov[4];
  #pragma unroll
  for (int i = 0; i < 32; i++){
    const int ip = ip0 + i;
    float wnext[4];
    #pragma unroll
    for (int c = 0; c < 4; c++)
      wnext[c] = (ip < 1023) ? W[(size_t)(c*1024 + ip + 1) * 1024 + o] : 0.f;
    float acc = 0.f;
    #pragma unroll
    for (int c = 0; c < 4; c++){
      acc += kk[c][0]*wnext[c] + kk[c][1]*wcur[c] + kk[c][2]*wprev[c];
      sc[c] += wcur[c];
    }
    ov[i >> 3][i & 7] = (short)f2bf(acc);
    #pragma unroll
    for (int c = 0; c < 4; c++){ wprev[c] = wcur[c]; wcur[c] = wnext[c]; }
  }
  unsigned short* drow = W1t + (size_t)(7168 + e*1024 + o) * 1024;
  #pragma unroll
  for (int q = 0; q < 4; q++) *(short8v*)&drow[ip0 + q*8] = ov[q];
  #pragma unroll
  for (int c = 0; c < 4; c++) atomicAdd(&scPart[(e*4 + c)*1024 + o], sc[c]);
}

__global__ void k_conv_bias(const float* __restrict__ convb, const float* __restrict__ convbL,
                            const float* __restrict__ scPart, float* __restrict__ b1cat){
  const int i = blockIdx.x * 256 + threadIdx.x;   // 2048
  const int e = i >> 10, o = i & 1023;
  float b = convbL[i];
  #pragma unroll
  for (int c = 0; c < 4; c++) b += convb[e*4 + c] * scPart[(e*4 + c)*1024 + o];
  b1cat[7168 + i] = b;
}

__global__ void k_biases(const float* mlp_b1, const float* bn_b1, const float* ln_b1, const float* sh_b1,
                         const float* mlp_b2, const float* bn_b2, const float* ln_b2, const float* sh_b2,
                         float* b1cat, float* b2cat){
  int i = blockIdx.x * 256 + threadIdx.x;   // 14336
  if (i < 7168){
    int r = i >> 10;
    float v;
    if (r < 2) v = mlp_b1[i];
    else if (r < 4) v = bn_b1[i - 2048];
    else if (r < 6) v = ln_b1[i - 4096];
    else v = sh_b1[i - 6144];
    b1cat[i] = v;
  } else {
    int j = i - 7168;
    int r = j >> 10;
    float v;
    if (r < 2) v = mlp_b2[j];
    else if (r < 4) v = bn_b2[j - 2048];
    else if (r < 6) v = ln_b2[j - 4096];
    else v = sh_b2[j - 6144];
    b2cat[j] = v;
  }
}

// ---------------------------------------------------------------------------
// Gate finalize: sum K-split partials + bias + modality, exact tanh (once per
// column, via LDS), fp32 GEMM2 (512x8), clip, top-4, softmax weights, usage.
// ---------------------------------------------------------------------------
__global__ __launch_bounds__(256) void k_gate_fin(const float* __restrict__ T,
                                                  const float* __restrict__ gW2,
                                                  const float* __restrict__ gb2,
                                                  const float* __restrict__ gb1,
                                                  const float* __restrict__ w1last,
                                                  const int* __restrict__ mod,
                                                  float* __restrict__ wgt,
                                                  float* __restrict__ usageTok){
  __shared__ float sT[4][512];
  const int tok0 = blockIdx.x * 4;
  #pragma unroll
  for (int i = 0; i < 8; i++){
    int idx = threadIdx.x + i * 256;           // 0..2047
    int tl = idx >> 9, k = idx & 511;
    int tok = tok0 + tl;
    float s = T[(size_t)tok * 512 + k] + T[(size_t)(NB + tok) * 512 + k]
            + gb1[k] + (float)mod[tok] * w1last[k];
    sT[tl][k] = tanhf(s);
  }
  __syncthreads();

  const int tl   = threadIdx.x >> 6;
  const int lane = threadIdx.x & 63;
  const int tok  = tok0 + tl;
  const int e = lane >> 3, sub = lane & 7;
  float p = 0.f;
  for (int k = sub; k < 512; k += 8) p += sT[tl][k] * gW2[k*8 + e];
  p += __shfl_xor(p, 1); p += __shfl_xor(p, 2); p += __shfl_xor(p, 4);
  float le[8];
  #pragma unroll
  for (int q = 0; q < 8; q++) le[q] = __shfl(p, q * 8);
  #pragma unroll
  for (int q = 0; q < 8; q++){
    float l = (le[q] + gb2[q]) / 0.7f;
    le[q] = fminf(fmaxf(l, -10.f), 10.f);
  }
  unsigned sel = 0; int idx4[4]; float bv4[4];
  #pragma unroll
  for (int t4 = 0; t4 < 4; t4++){
    float best = -1e30f; int bi = 0;
    for (int q = 0; q < 8; q++)
      if (!((sel >> q) & 1u) && le[q] > best){ best = le[q]; bi = q; }
    sel |= 1u << bi; idx4[t4] = bi; bv4[t4] = best;
  }
  const float mx = bv4[0];
  float s4 = 0.f, w4[4];
  #pragma unroll
  for (int t4 = 0; t4 < 4; t4++){ w4[t4] = expf(bv4[t4] - mx); s4 += w4[t4]; }
  float su = 0.f, us[8];
  #pragma unroll
  for (int q = 0; q < 8; q++){ us[q] = expf(le[q] - mx); su += us[q]; }
  if (lane == 0){
    float wr[8] = {0,0,0,0,0,0,0,0};
    #pragma unroll
    for (int t4 = 0; t4 < 4; t4++) wr[idx4[t4]] = w4[t4] / s4;
    const float inv = 1.f / su;
    #pragma unroll
    for (int q = 0; q < 8; q++) wgt[(size_t)tok*8 + q] = wr[q];
    #pragma unroll
    for (int q = 0; q < 8; q++) usageTok[(size_t)tok*8 + q] = us[q] * inv;
  }
}

__global__ __launch_bounds__(256) void k_aux(const float* __restrict__ usageTok, float* __restrict__ auxp){
  __shared__ float red[256][8];
  float a[8] = {0,0,0,0,0,0,0,0};
  for (int r = threadIdx.x; r < NB; r += 256){
    float4v v0 = *(const float4v*)&usageTok[(size_t)r * 8];
    float4v v1 = *(const float4v*)&usageTok[(size_t)r * 8 + 4];
    #pragma unroll
    for (int j = 0; j < 4; j++){ a[j] += v0[j]; a[4+j] += v1[j]; }
  }
  #pragma unroll
  for (int q = 0; q < 8; q++) red[threadIdx.x][q] = a[q];
  __syncthreads();
  if (threadIdx.x == 0){
    float s[8] = {0,0,0,0,0,0,0,0};
    for (int t = 0; t < 256; t++)
      #pragma unroll
      for (int q = 0; q < 8; q++) s[q] += red[t][q];
    float acc = 0.f;
    for (int q = 0; q < 8; q++){
      float u = s[q] * (1.f / 4096.f);
      acc += 0.125f * (-2.0794415f - logf(u + 1e-10f));
    }
    auxp[0] = acc * 0.125f;
  }
}

// ---------------------------------------------------------------------------
// BatchNorm (batch stats) over H cols 2048..4095: 2-pass, row-major coalesced.
// ---------------------------------------------------------------------------
__global__ __launch_bounds__(256) void k_bn_stats(const unsigned short* __restrict__ H,
                                                  float* __restrict__ colstats){
  const int r0 = blockIdx.x * 64;
  const int c0 = threadIdx.x * 8;
  float s[8], s2[8];
  #pragma unroll
  for (int j = 0; j < 8; j++){ s[j] = 0.f; s2[j] = 0.f; }
  for (int r = 0; r < 64; r++){
    short8v v = *(const short8v*)&H[(size_t)(r0 + r) * 7168 + 2048 + c0];
    #pragma unroll
    for (int j = 0; j < 8; j++){
      float f = bf2f((unsigned short)v[j]);
      s[j] += f; s2[j] += f * f;
    }
  }
  #pragma unroll
  for (int j = 0; j < 8; j++){
    atomicAdd(&colstats[c0 + j], s[j]);
    atomicAdd(&colstats[2048 + c0 + j], s2[j]);
  }
}

__global__ __launch_bounds__(256) void k_bn_apply(unsigned short* __restrict__ H,
    const float* __restrict__ colstats,
    const float* __restrict__ bn_g, const float* __restrict__ bn_be){
  const int r0 = blockIdx.x * 16;
  const int c0 = threadIdx.x * 8;
  float mul[8], add[8];
  #pragma unroll
  for (int j = 0; j < 8; j++){
    const int c = c0 + j;
    float m   = colstats[c] * (1.f / NB);
    float var = colstats[2048 + c] * (1.f / NB) - m * m;
    float inv = 1.f / sqrtf(var + 1e-5f);
    const int e = c >> 10, cc = c & 1023;
    float g = bn_g[e*1024 + cc], b = bn_be[e*1024 + cc];
    mul[j] = g * inv;
    add[j] = b - m * g * inv;
  }
  for (int r = 0; r < 16; r++){
    unsigned short* p = &H[(size_t)(r0 + r) * 7168 + 2048 + c0];
    short8v v = *(const short8v*)p;
    short8v o;
    #pragma unroll
    for (int j = 0; j < 8; j++)
      o[j] = (short)f2bf(bf2f((unsigned short)v[j]) * mul[j] + add[j]);
    *(short8v*)p = o;
  }
}

// ---------------------------------------------------------------------------
// Row LayerNorm for ln0/ln1/shared slices of H, in place
// ---------------------------------------------------------------------------
__global__ __launch_bounds__(128) void k_ln(unsigned short* __restrict__ H,
    const float* __restrict__ ln_g, const float* __restrict__ ln_be,
    const float* __restrict__ sh_g, const float* __restrict__ sh_be){
  const int row = blockIdx.x, sl = blockIdx.y;
  unsigned short* p = H + (size_t)row * 7168 + 4096 + sl * 1024;
  const int t = threadIdx.x, lane = t & 63, w = t >> 6;
  short8v raw = *(const short8v*)&p[t * 8];
  float v[8]; float s = 0.f, s2 = 0.f;
  #pragma unroll
  for (int j = 0; j < 8; j++){ v[j] = bf2f((unsigned short)raw[j]); s += v[j]; s2 += v[j]*v[j]; }
  #pragma unroll
  for (int d = 1; d < 64; d <<= 1){ s += __shfl_xor(s, d); s2 += __shfl_xor(s2, d); }
  __shared__ float red[4];
  if (lane == 0){ red[w*2] = s; red[w*2+1] = s2; }
  __syncthreads();
  float ts = red[0] + red[2], tq = red[1] + red[3];
  float m   = ts * (1.f / 1024.f);
  float var = tq * (1.f / 1024.f) - m*m;
  float inv = 1.f / sqrtf(var + 1e-5f);
  const float* gp = (sl == 0) ? ln_g : (sl == 1) ? ln_g + 1024 : sh_g;
  const float* bp = (sl == 0) ? ln_be : (sl == 1) ? ln_be + 1024 : sh_be;
  short8v outv;
  #pragma unroll
  for (int j = 0; j < 8; j++){
    int cc = t*8 + j;
    outv[j] = (short)f2bf((v[j] - m) * inv * gp[cc] + bp[cc]);
  }
  *(short8v*)&p[t * 8] = outv;
}

// ---------------------------------------------------------------------------
// private = sum_e wgt[b][e] * expert_out[e][b,:]
// ---------------------------------------------------------------------------
__global__ __launch_bounds__(256) void k_combine(const unsigned short* __restrict__ eolin,
    const unsigned short* __restrict__ eoc, const float* __restrict__ wgt, float* __restrict__ priv){
  const int i = blockIdx.x * 256 + threadIdx.x;  // 524288
  const int b = i >> 7;
  const int c = (i & 127) * 8;
  const float* w = wgt + (size_t)b * 8;
  float acc[8];
  #pragma unroll
  for (int j = 0; j < 8; j++) acc[j] = 0.f;
  const int emap[6] = {0, 1, 2, 3, 6, 7};
  #pragma unroll
  for (int r = 0; r < 6; r++){
    float we = w[emap[r]];
    short8v v = *(const short8v*)&eolin[((size_t)r * NB + b) * 1024 + c];
    #pragma unroll
    for (int j = 0; j < 8; j++) acc[j] += we * bf2f((unsigned short)v[j]);
  }
  #pragma unroll
  for (int e2 = 0; e2 < 2; e2++){
    float we = w[4 + e2];
    short8v v = *(const short8v*)&eoc[((size_t)e2 * NB + b) * 1024 + c];
    #pragma unroll
    for (int j = 0; j < 8; j++) acc[j] += we * bf2f((unsigned short)v[j]);
  }
  float4v o0 = {acc[0], acc[1], acc[2], acc[3]};
  float4v o1 = {acc[4], acc[5], acc[6], acc[7]};
  float4v* dst = (float4v*)&priv[(size_t)b * 1024 + c];
  dst[0] = o0; dst[1] = o1;
}

// ---------------------------------------------------------------------------
// Host launch
// ---------------------------------------------------------------------------
extern "C" void kernel_launch(void* const* d_in, const int* in_sizes, int n_in,
                              void* d_out, int out_size, void* d_ws, size_t ws_size,
                              hipStream_t stream){
  const float* x      = (const float*)d_in[0];
  const int*   modal  = (const int*)d_in[1];
  const float* mlp_W1 = (const float*)d_in[2];
  const float* mlp_b1 = (const float*)d_in[3];
  const float* mlp_W2 = (const float*)d_in[4];
  const float* mlp_b2 = (const float*)d_in[5];
  const float* bn_W1  = (const float*)d_in[6];
  const float* bn_b1  = (const float*)d_in[7];
  const float* bn_g   = (const float*)d_in[8];
  const float* bn_be  = (const float*)d_in[9];
  const float* bn_W2  = (const float*)d_in[10];
  const float* bn_b2  = (const float*)d_in[11];
  const float* conv_k = (const float*)d_in[12];
  const float* conv_b = (const float*)d_in[13];
  const float* conv_W = (const float*)d_in[14];
  const float* conv_bL= (const float*)d_in[15];
  const float* ln_W1  = (const float*)d_in[16];
  const float* ln_b1  = (const float*)d_in[17];
  const float* ln_g   = (const float*)d_in[18];
  const float* ln_be  = (const float*)d_in[19];
  const float* ln_W2  = (const float*)d_in[20];
  const float* ln_b2  = (const float*)d_in[21];
  const float* sh_W1  = (const float*)d_in[22];
  const float* sh_b1  = (const float*)d_in[23];
  const float* sh_g   = (const float*)d_in[24];
  const float* sh_be  = (const float*)d_in[25];
  const float* sh_W2  = (const float*)d_in[26];
  const float* sh_b2  = (const float*)d_in[27];
  const float* g_W1   = (const float*)d_in[28];
  const float* g_b1   = (const float*)d_in[29];
  const float* g_W2   = (const float*)d_in[30];
  const float* g_b2   = (const float*)d_in[31];

  char* ws = (char*)d_ws;
  size_t o_xb   = 0;
  size_t o_xlo  = o_xb  + 8388608ull;
  size_t o_W1t  = o_xlo + 8388608ull;    // [9216][1024] bf16
  size_t o_W2t  = o_W1t + 18874368ull;   // [7168][1024] bf16
  size_t o_Wg   = o_W2t + 14680064ull;   // [512][3072] bf16
  size_t o_H    = o_Wg  + 3145728ull;    // [4096][7168] bf16 (T aliases first 16MB)
  size_t o_eoc  = o_H   + 58720256ull;   // [2][4096][1024] bf16
  size_t o_eol  = o_eoc + 16777216ull;   // [6][4096][1024] bf16
  size_t o_b1   = o_eol + 50331648ull;   // [9216] f32
  size_t o_b2   = o_b1  + 36864ull;      // [7168] f32
  size_t o_wgt  = o_b2  + 28672ull;      // [4096][8] f32
  size_t o_ut   = o_wgt + 131072ull;     // [4096][8] f32 usage probs
  size_t o_scp  = o_ut  + 131072ull;     // [2][4][1024] f32 conv colsum partials
  size_t o_cst  = o_scp + 32768ull;      // [2][2048] f32 bn colstats

  unsigned short* xb    = (unsigned short*)(ws + o_xb);
  unsigned short* xlo   = (unsigned short*)(ws + o_xlo);
  unsigned short* W1t   = (unsigned short*)(ws + o_W1t);
  unsigned short* W2t   = (unsigned short*)(ws + o_W2t);
  unsigned short* Wg3t  = (unsigned short*)(ws + o_Wg);
  unsigned short* H     = (unsigned short*)(ws + o_H);
  float*          T     = (float*)(ws + o_H);   // dead before H is written
  unsigned short* eoc   = (unsigned short*)(ws + o_eoc);
  unsigned short* eolin = (unsigned short*)(ws + o_eol);
  float*          b1cat = (float*)(ws + o_b1);
  float*          b2cat = (float*)(ws + o_b2);
  float*          wgt   = (float*)(ws + o_wgt);
  float*          usageTok = (float*)(ws + o_ut);
  float*          scPart   = (float*)(ws + o_scp);
  float*          colstats = (float*)(ws + o_cst);

  float* outF   = (float*)d_out;
  float* shared = outF;                       // [4096][1024]
  float* priv   = outF + (size_t)NB * 1024;   // [4096][1024]
  float* auxp   = outF + (size_t)2 * NB * 1024; // [1]

  hipMemsetAsync(scPart, 0, 32768, stream);
  hipMemsetAsync(colstats, 0, 16384, stream);

  k_cast_x<<<4096, 256, 0, stream>>>(x, xb, xlo);

  TpArgs tp;
  for (int e = 0; e < 2; e++){
    tp.src[0 + e] = mlp_W1 + (size_t)e * 1048576;
    tp.src[2 + e] = bn_W1  + (size_t)e * 1048576;
    tp.src[4 + e] = ln_W1  + (size_t)e * 1048576;
  }
  tp.src[6] = sh_W1;
  for (int e = 0; e < 2; e++){
    tp.src[7 + e]  = mlp_W2 + (size_t)e * 1048576;
    tp.src[9 + e]  = bn_W2  + (size_t)e * 1048576;
    tp.src[11 + e] = ln_W2  + (size_t)e * 1048576;
  }
  tp.src[13] = sh_W2;
  for (int s = 0; s < 7; s++)  tp.dst[s] = W1t + (size_t)s * 1048576;
  for (int s = 7; s < 14; s++) tp.dst[s] = W2t + (size_t)(s - 7) * 1048576;
  k_transpose<<<dim3(32, 32, 14), dim3(32, 8), 0, stream>>>(tp);

  k_gateW<<<dim3(32, 16), dim3(32, 8), 0, stream>>>(g_W1, Wg3t);
  k_convW<<<dim3(4, 32, 2), 256, 0, stream>>>(conv_k, conv_W, W1t, scPart);
  k_conv_bias<<<8, 256, 0, stream>>>(conv_b, conv_bL, scPart, b1cat);
  k_biases<<<56, 256, 0, stream>>>(mlp_b1, bn_b1, ln_b1, sh_b1, mlp_b2, bn_b2, ln_b2, sh_b2, b1cat, b2cat);

  // ---- gate (K-split x2) ----
  GemmArgs ga = {};
  ga.A = xb; ga.A2 = xlo; ga.Bt = Wg3t; ga.lda = 1024; ga.K = 3072;
  ga.T = T;
  k_gemm<2><<<dim3(32, 4, 2), 256, 0, stream>>>(ga);
  k_gate_fin<<<1024, 256, 0, stream>>>(T, g_W2, g_b2, g_b1, g_W1 + (size_t)1024 * 512,
                                       modal, wgt, usageTok);
  k_aux<<<1, 256, 0, stream>>>(usageTok, auxp);

  // ---- fused layer 1 (all first-layer GEMMs + conv experts) ----
  GemmArgs g1 = {};
  g1.A = xb; g1.Bt = W1t; g1.lda = 1024; g1.K = 1024;
  g1.bias = b1cat; g1.H = H; g1.eoc = eoc;
  k_gemm<0><<<dim3(32, 72), 256, 0, stream>>>(g1);

  k_bn_stats<<<64, 256, 0, stream>>>(H, colstats);
  k_bn_apply<<<256, 256, 0, stream>>>(H, colstats, bn_g, bn_be);
  k_ln<<<dim3(4096, 3), 128, 0, stream>>>(H, ln_g, ln_be, sh_g, sh_be);

  // ---- fused layer 2 (6 private experts + shared) ----
  GemmArgs g2 = {};
  g2.A = H; g2.Bt = W2t; g2.lda = 7168; g2.K = 1024;
  g2.bias = b2cat; g2.eolin = eolin; g2.outsh = shared;
  k_gemm<1><<<dim3(32, 56), 256, 0, stream>>>(g2);

  k_combine<<<2048, 256, 0, stream>>>(eolin, eoc, wgt, priv);
}